// Round 4
// baseline (798.942 us; speedup 1.0000x reference)
//
#include <hip/hip_runtime.h>
#include <math.h>

typedef _Float16 f16;
typedef _Float16 f16x8 __attribute__((ext_vector_type(8)));
typedef float f32x4 __attribute__((ext_vector_type(4)));
typedef float f32x16 __attribute__((ext_vector_type(16)));

#define NB 16
#define SS 2048
#define DD 512

// async global->LDS, 16B per lane; LDS dst must be wave-uniform base + lane*16
__device__ __forceinline__ void gl_lds16(const void* g, void* l) {
  __builtin_amdgcn_global_load_lds(
      (const __attribute__((address_space(1))) unsigned int*)g,
      (__attribute__((address_space(3))) unsigned int*)l, 16, 0, 0);
}

// ---------------- cast x (fp32) -> fp16, 8 elems/thread ----------------
__global__ __launch_bounds__(256) void cast_kernel(const float* __restrict__ x,
                                                   f16* __restrict__ o) {
  size_t i = (size_t)blockIdx.x * 256 + threadIdx.x;
  const float4* p = (const float4*)x + i * 2;
  float4 a = p[0], b = p[1];
  f16x8 v = {(f16)a.x, (f16)a.y, (f16)a.z, (f16)a.w,
             (f16)b.x, (f16)b.y, (f16)b.z, (f16)b.w};
  *((f16x8*)o + i) = v;
}

// ---------------- transpose 512x512 weight, fp32 -> fp16 ----------------
__global__ __launch_bounds__(256) void transpose_kernel(const float* __restrict__ W,
                                                        f16* __restrict__ Wt) {
  __shared__ float t[32][33];
  int bx = blockIdx.x * 32, by = blockIdx.y * 32;
  int c = threadIdx.x & 31, r0 = threadIdx.x >> 5;
  for (int r = r0; r < 32; r += 8) t[r][c] = W[(size_t)(by + r) * DD + bx + c];
  __syncthreads();
  for (int r = r0; r < 32; r += 8) Wt[(size_t)(bx + r) * DD + by + c] = (f16)t[c][r];
}

// ---------------- GEMM: C[M][N] = A[M][K=512] * Bt[N][K=512]^T ----------------
// 128x128 tile, BK=32, 4 waves (2x2 of 64x64), 16x16x32_f16 MFMA. (R2: proven)
__global__ __launch_bounds__(256) void gemm_kernel(
    const f16* __restrict__ A, long sAb, const f16* __restrict__ Bt, long sBb,
    f16* __restrict__ C, long sCb, int ldc, const float* __restrict__ bias,
    int bias_row, float scale) {
  A += (size_t)blockIdx.z * sAb;
  Bt += (size_t)blockIdx.z * sBb;
  C += (size_t)blockIdx.z * sCb;
  const int m0 = blockIdx.y * 128, n0 = blockIdx.x * 128;
  __shared__ f16 Ash[128 * 32];
  __shared__ f16 Bsh[128 * 32];
  const int tid = threadIdx.x, lane = tid & 63, wave = tid >> 6;
  const int wm = wave & 1, wn = wave >> 1;
  const int l15 = lane & 15, lq = lane >> 4;
  f32x4 acc[4][4] = {};
  const int srow = tid >> 2, part = tid & 3;
  const f16* gA = A + (size_t)(m0 + srow) * DD + part * 8;
  const f16* gB = Bt + (size_t)(n0 + srow) * DD + part * 8;
  f16* lA = &Ash[tid * 8];
  f16* lB = &Bsh[tid * 8];
  for (int kt = 0; kt < 16; ++kt) {
    gl_lds16(gA + kt * 32, lA);
    gl_lds16(gA + 64 * DD + kt * 32, lA + 2048);
    gl_lds16(gB + kt * 32, lB);
    gl_lds16(gB + 64 * DD + kt * 32, lB + 2048);
    __syncthreads();
    f16x8 af[4], bf[4];
#pragma unroll
    for (int i = 0; i < 4; ++i)
      af[i] = *(const f16x8*)&Ash[(64 * wm + 16 * i + l15) * 32 + lq * 8];
#pragma unroll
    for (int j = 0; j < 4; ++j)
      bf[j] = *(const f16x8*)&Bsh[(64 * wn + 16 * j + l15) * 32 + lq * 8];
#pragma unroll
    for (int i = 0; i < 4; ++i)
#pragma unroll
      for (int j = 0; j < 4; ++j)
        acc[i][j] = __builtin_amdgcn_mfma_f32_16x16x32_f16(af[i], bf[j], acc[i][j], 0, 0, 0);
    __syncthreads();
  }
#pragma unroll
  for (int i = 0; i < 4; ++i) {
    int rb = 64 * wm + 16 * i + lq * 4;
#pragma unroll
    for (int j = 0; j < 4; ++j) {
      int cc = n0 + 64 * wn + 16 * j + l15;
#pragma unroll
      for (int r = 0; r < 4; ++r) {
        int rr = m0 + rb + r;
        float bv = bias_row ? bias[rr] : bias[cc];
        C[(size_t)rr * ldc + cc] = (f16)((acc[i][j][r] + bv) * scale);
      }
    }
  }
}

// ---------------- fragment repack ----------------
// in: tile of 32 rows x 512 cols (rowStride elems between rows).
// out: 32 slots of [lane][8]: slot ck, lane (l31,lh) = in[row=l31][16*ck+8*lh..+8]
__global__ __launch_bounds__(256) void repack_kernel(
    const f16* __restrict__ in, f16* __restrict__ out, long inQ, long inSb,
    long outQ, long outSb, int sbN, int rowStride) {
  int q = blockIdx.x / sbN, sb = blockIdx.x % sbN;
  in += (size_t)q * inQ + (size_t)sb * inSb;
  out += (size_t)q * outQ + (size_t)sb * outSb;
  __shared__ f16 T[32][520];  // +8 pad
  const int tid = threadIdx.x;
#pragma unroll
  for (int p = 0; p < 8; ++p) {
    int idx = p * 2048 + tid * 8;
    int row = idx >> 9, col = idx & 511;
    *(f16x8*)&T[row][col] = *(const f16x8*)(in + (size_t)row * rowStride + col);
  }
  __syncthreads();
  const int lane = tid & 63, l31 = lane & 31, lh = lane >> 5;
#pragma unroll
  for (int p = 0; p < 8; ++p) {
    int ck = p * 4 + (tid >> 6);
    f16x8 v = *(const f16x8*)&T[l31][ck * 16 + lh * 8];
    *(f16x8*)(out + p * 2048 + tid * 8) = v;
  }
}

__device__ __forceinline__ float max4(float4 s) {
  return fmaxf(fmaxf(s.x, s.y), fmaxf(s.z, s.w));
}
__device__ __forceinline__ float4 expm4(float4 s, float m) {
  return make_float4(__expf(s.x - m), __expf(s.y - m), __expf(s.z - m), __expf(s.w - m));
}

// ---------------- flash attention (fragment-major K/V, XCD-pinned grid) ----
// 1-D grid of 512: id -> round=id>>8, xcd=id&7, qt=(id&255)>>3; b=round*8+xcd.
// With 1 block/CU and id%8->XCD round-robin, each XCD runs one batch per
// round: K+V = 4 MB = one XCD-L2. [R3: only change vs R2 kernel]
__global__ __launch_bounds__(512, 2) void attn_kernel(
    const f16* __restrict__ Q, const f16* __restrict__ Kp,
    const f16* __restrict__ Vp, float* __restrict__ out) {
  const int id = blockIdx.x;
  const int b = ((id >> 8) << 3) | (id & 7);
  const int qt = (id & 255) >> 3;
  const int q0 = qt * 64;
  const int tid = threadIdx.x, lane = tid & 63, wave = tid >> 6;
  const int wm = wave >> 2, wn = wave & 3;
  const int l31 = lane & 31, lh = lane >> 5;
  __shared__ float Ssh[64][132];
  __shared__ f16 Psh[64][136];
  __shared__ float red[64];

  const f16* qp = Q + ((size_t)(b * SS + q0 + 32 * wm + l31)) * DD + lh * 8;
  f16x8 qf[32];
#pragma unroll
  for (int ks = 0; ks < 32; ++ks) qf[ks] = *(const f16x8*)(qp + ks * 16);

  f32x16 acco[4] = {};
  const int srow = tid >> 3, sseg = tid & 7;
  float m_i = -1e30f, l_i = 0.f;

  const f16* kbase = Kp + ((size_t)(b * 64 + wn) * 32) * 512 + lane * 8;
  const f16* vbase = Vp + ((size_t)(b * 16 + 4 * wn) * 128) * 512 + lane * 8;

  for (int it = 0; it < 16; ++it) {
    // ---- stage 1: S(64x128) = Q Kt ----
    f32x16 sa = {};
    const f16* kp = kbase + (size_t)it * 4 * 32 * 512;
#pragma unroll
    for (int ks = 0; ks < 32; ++ks) {
      f16x8 kf = *(const f16x8*)(kp + ks * 512);
      sa = __builtin_amdgcn_mfma_f32_32x32x16_f16(qf[ks], kf, sa, 0, 0, 0);
    }
#pragma unroll
    for (int r = 0; r < 16; ++r) {
      int rr = (r & 3) + 8 * (r >> 2) + 4 * lh;
      Ssh[32 * wm + rr][32 * wn + l31] = sa[r];
    }
    __syncthreads();
    // ---- stage 2: online softmax ----
    float4 s0 = *(const float4*)&Ssh[srow][sseg * 16 + 0];
    float4 s1 = *(const float4*)&Ssh[srow][sseg * 16 + 4];
    float4 s2 = *(const float4*)&Ssh[srow][sseg * 16 + 8];
    float4 s3 = *(const float4*)&Ssh[srow][sseg * 16 + 12];
    float mx = fmaxf(fmaxf(max4(s0), max4(s1)), fmaxf(max4(s2), max4(s3)));
    mx = fmaxf(mx, __shfl_xor(mx, 1));
    mx = fmaxf(mx, __shfl_xor(mx, 2));
    mx = fmaxf(mx, __shfl_xor(mx, 4));
    float m_new = fmaxf(m_i, mx);
    float4 e0 = expm4(s0, m_new), e1 = expm4(s1, m_new);
    float4 e2 = expm4(s2, m_new), e3 = expm4(s3, m_new);
    float sum = e0.x + e0.y + e0.z + e0.w + e1.x + e1.y + e1.z + e1.w +
                e2.x + e2.y + e2.z + e2.w + e3.x + e3.y + e3.z + e3.w;
    sum += __shfl_xor(sum, 1);
    sum += __shfl_xor(sum, 2);
    sum += __shfl_xor(sum, 4);
    float alpha = __expf(m_i - m_new);
    l_i = l_i * alpha + sum;
    m_i = m_new;
    if (sseg == 0) red[srow] = alpha;
    f16x8 ph0 = {(f16)e0.x, (f16)e0.y, (f16)e0.z, (f16)e0.w,
                 (f16)e1.x, (f16)e1.y, (f16)e1.z, (f16)e1.w};
    f16x8 ph1 = {(f16)e2.x, (f16)e2.y, (f16)e2.z, (f16)e2.w,
                 (f16)e3.x, (f16)e3.y, (f16)e3.z, (f16)e3.w};
    *(f16x8*)&Psh[srow][sseg * 16] = ph0;
    *(f16x8*)&Psh[srow][sseg * 16 + 8] = ph1;
    __syncthreads();
    // ---- stage 3: O = O*alpha + P V ----
    float al[16];
#pragma unroll
    for (int g = 0; g < 4; ++g) {
      float4 t4 = *(const float4*)&red[32 * wm + 8 * g + 4 * lh];
      al[4 * g + 0] = t4.x; al[4 * g + 1] = t4.y;
      al[4 * g + 2] = t4.z; al[4 * g + 3] = t4.w;
    }
#pragma unroll
    for (int t = 0; t < 4; ++t)
#pragma unroll
      for (int r = 0; r < 16; ++r) acco[t][r] *= al[4 * (r >> 2) + (r & 3)];
    const f16* vp = vbase + (size_t)it * 8 * 512;
#pragma unroll
    for (int ks = 0; ks < 8; ++ks) {
      f16x8 pf = *(const f16x8*)&Psh[32 * wm + l31][ks * 16 + lh * 8];
#pragma unroll
      for (int t = 0; t < 4; ++t) {
        f16x8 vf = *(const f16x8*)(vp + ((size_t)t * 128 + ks) * 512);
        acco[t] = __builtin_amdgcn_mfma_f32_32x32x16_f16(pf, vf, acco[t], 0, 0, 0);
      }
    }
  }
  __syncthreads();
  if (sseg == 0) red[srow] = 1.0f / l_i;
  __syncthreads();
  float li[16];
#pragma unroll
  for (int g = 0; g < 4; ++g) {
    float4 t4 = *(const float4*)&red[32 * wm + 8 * g + 4 * lh];
    li[4 * g + 0] = t4.x; li[4 * g + 1] = t4.y;
    li[4 * g + 2] = t4.z; li[4 * g + 3] = t4.w;
  }
  const size_t obase = ((size_t)b * SS + q0 + 32 * wm) * DD + 128 * wn + l31;
#pragma unroll
  for (int t = 0; t < 4; ++t)
#pragma unroll
    for (int r = 0; r < 16; ++r) {
      int rr = (r & 3) + 8 * (r >> 2) + 4 * lh;
      out[obase + (size_t)rr * DD + 32 * t] = acco[t][r] * li[4 * (r >> 2) + (r & 3)];
    }
}

extern "C" void kernel_launch(void* const* d_in, const int* in_sizes, int n_in,
                              void* d_out, int out_size, void* d_ws, size_t ws_size,
                              hipStream_t stream) {
  const float* x = (const float*)d_in[0];
  const float* Wq = (const float*)d_in[1];
  const float* bq = (const float*)d_in[2];
  const float* Wk = (const float*)d_in[3];
  const float* bk = (const float*)d_in[4];
  const float* Wv = (const float*)d_in[5];
  const float* bv = (const float*)d_in[6];
  float* out = (float*)d_out;
  f16* ws = (f16*)d_ws;
  const size_t NX = (size_t)NB * SS * DD;  // 16,777,216
  f16* xh = ws;
  f16* Qh = ws + NX;
  f16* Kh = ws + 2 * NX;
  f16* Vth = ws + 3 * NX;
  f16* WqT = ws + 4 * NX;
  f16* WkT = WqT + DD * DD;
  f16* WvT = WkT + DD * DD;
  f16* Kp = xh;  // xh dead after the 3 GEMMs
  f16* Vp = Kh;  // Kh dead after K-repack

  cast_kernel<<<NX / 8 / 256, 256, 0, stream>>>(x, xh);
  dim3 tg(16, 16);
  transpose_kernel<<<tg, 256, 0, stream>>>(Wq, WqT);
  transpose_kernel<<<tg, 256, 0, stream>>>(Wk, WkT);
  transpose_kernel<<<tg, 256, 0, stream>>>(Wv, WvT);
  gemm_kernel<<<dim3(4, 256, 1), 256, 0, stream>>>(xh, 0, WqT, 0, Qh, 0, DD, bq, 0, 0.125f);
  gemm_kernel<<<dim3(4, 256, 1), 256, 0, stream>>>(xh, 0, WkT, 0, Kh, 0, DD, bk, 0, 1.0f);
  gemm_kernel<<<dim3(16, 4, NB), 256, 0, stream>>>(WvT, 0, xh, (long)SS * DD, Vth,
                                                   (long)DD * SS, SS, bv, 1, 1.0f);
  repack_kernel<<<NB * 64, 256, 0, stream>>>(Kh, Kp, 16384, 0, 16384, 0, 1, DD);
  repack_kernel<<<NB * 16 * 4, 256, 0, stream>>>(Vth, Vp, 65536, 512, 65536, 16384, 4, SS);
  // XCD-pinned 1-D grid (see attn_kernel header comment)
  attn_kernel<<<512, 512, 0, stream>>>(Qh, Kp, Vp, out);
}

// Round 5
// 644.619 us; speedup vs baseline: 1.2394x; 1.2394x over previous
//
#include <hip/hip_runtime.h>
#include <math.h>

typedef _Float16 f16;
typedef _Float16 f16x8 __attribute__((ext_vector_type(8)));
typedef float f32x4 __attribute__((ext_vector_type(4)));

#define NB 16
#define SS 2048
#define DD 512

// async global->LDS, 16B per lane; LDS dst = wave-uniform base + lane*16
__device__ __forceinline__ void gl_lds16(const void* g, void* l) {
  __builtin_amdgcn_global_load_lds(
      (const __attribute__((address_space(1))) unsigned int*)g,
      (__attribute__((address_space(3))) unsigned int*)l, 16, 0, 0);
}

// ---------------- cast x (fp32) -> fp16, 8 elems/thread ----------------
__global__ __launch_bounds__(256) void cast_kernel(const float* __restrict__ x,
                                                   f16* __restrict__ o) {
  size_t i = (size_t)blockIdx.x * 256 + threadIdx.x;
  const float4* p = (const float4*)x + i * 2;
  float4 a = p[0], b = p[1];
  f16x8 v = {(f16)a.x, (f16)a.y, (f16)a.z, (f16)a.w,
             (f16)b.x, (f16)b.y, (f16)b.z, (f16)b.w};
  *((f16x8*)o + i) = v;
}

// ---------------- transpose 512x512 weight, fp32 -> fp16 ----------------
__global__ __launch_bounds__(256) void transpose_kernel(const float* __restrict__ W,
                                                        f16* __restrict__ Wt) {
  __shared__ float t[32][33];
  int bx = blockIdx.x * 32, by = blockIdx.y * 32;
  int c = threadIdx.x & 31, r0 = threadIdx.x >> 5;
  for (int r = r0; r < 32; r += 8) t[r][c] = W[(size_t)(by + r) * DD + bx + c];
  __syncthreads();
  for (int r = r0; r < 32; r += 8) Wt[(size_t)(bx + r) * DD + by + c] = (f16)t[c][r];
}

// ---------------- GEMM: C[M][N] = A[M][K=512] * Bt[N][K=512]^T ----------------
// 128x128 tile, BK=32, 4 waves (2x2 of 64x64), 16x16x32_f16 MFMA. (R2: proven)
__global__ __launch_bounds__(256) void gemm_kernel(
    const f16* __restrict__ A, long sAb, const f16* __restrict__ Bt, long sBb,
    f16* __restrict__ C, long sCb, int ldc, const float* __restrict__ bias,
    int bias_row, float scale) {
  A += (size_t)blockIdx.z * sAb;
  Bt += (size_t)blockIdx.z * sBb;
  C += (size_t)blockIdx.z * sCb;
  const int m0 = blockIdx.y * 128, n0 = blockIdx.x * 128;
  __shared__ f16 Ash[128 * 32];
  __shared__ f16 Bsh[128 * 32];
  const int tid = threadIdx.x, lane = tid & 63, wave = tid >> 6;
  const int wm = wave & 1, wn = wave >> 1;
  const int l15 = lane & 15, lq = lane >> 4;
  f32x4 acc[4][4] = {};
  const int srow = tid >> 2, part = tid & 3;
  const f16* gA = A + (size_t)(m0 + srow) * DD + part * 8;
  const f16* gB = Bt + (size_t)(n0 + srow) * DD + part * 8;
  f16* lA = &Ash[tid * 8];
  f16* lB = &Bsh[tid * 8];
  for (int kt = 0; kt < 16; ++kt) {
    gl_lds16(gA + kt * 32, lA);
    gl_lds16(gA + 64 * DD + kt * 32, lA + 2048);
    gl_lds16(gB + kt * 32, lB);
    gl_lds16(gB + 64 * DD + kt * 32, lB + 2048);
    __syncthreads();
    f16x8 af[4], bf[4];
#pragma unroll
    for (int i = 0; i < 4; ++i)
      af[i] = *(const f16x8*)&Ash[(64 * wm + 16 * i + l15) * 32 + lq * 8];
#pragma unroll
    for (int j = 0; j < 4; ++j)
      bf[j] = *(const f16x8*)&Bsh[(64 * wn + 16 * j + l15) * 32 + lq * 8];
#pragma unroll
    for (int i = 0; i < 4; ++i)
#pragma unroll
      for (int j = 0; j < 4; ++j)
        acc[i][j] = __builtin_amdgcn_mfma_f32_16x16x32_f16(af[i], bf[j], acc[i][j], 0, 0, 0);
    __syncthreads();
  }
#pragma unroll
  for (int i = 0; i < 4; ++i) {
    int rb = 64 * wm + 16 * i + lq * 4;
#pragma unroll
    for (int j = 0; j < 4; ++j) {
      int cc = n0 + 64 * wn + 16 * j + l15;
#pragma unroll
      for (int r = 0; r < 4; ++r) {
        int rr = m0 + rb + r;
        float bv = bias_row ? bias[rr] : bias[cc];
        C[(size_t)rr * ldc + cc] = (f16)((acc[i][j][r] + bv) * scale);
      }
    }
  }
}

// ---------------- flash attention, R4 redesign ----------------
// M=128 Q-rows/block, 256 blocks (1/CU). 8 waves; wave w owns rows 16w..16w+16
// fully: in-register online softmax, zero cross-wave stats. KN=32 keys/iter,
// K via global_load_lds DMA (row-per-instr into 520-stride LDS), V via 2
// vector loads + ds_write (40-stride LDS), both double-buffered, ONE barrier
// per iter. O accumulated over D in 2 passes of 256 cols (QK recomputed) to
// keep acc at 64 VGPRs; total regs ~195 < 256 -> 2 waves/SIMD.
// 16x16x32 layouts (m89-verified): A[m=l15][k=lq*8+j], B[k=lq*8+j][n=l15],
// C col=l15, row=lq*4+r.
__global__ __launch_bounds__(512, 2) void attn_kernel(
    const f16* __restrict__ Q, const f16* __restrict__ K,
    const f16* __restrict__ Vt, float* __restrict__ out) {
  const int id = blockIdx.x;
  const int b = (id & 7) + ((id >> 7) << 3);  // XCD x gets batches {x, x+8}
  const int qt = (id >> 3) & 15;
  const int tid = threadIdx.x, lane = tid & 63, wave = tid >> 6;
  const int l15 = lane & 15, lq = lane >> 4;

  __shared__ __align__(16) f16 Kl[2][32][520];  // [key][d], stride 520 (2-way banks)
  __shared__ __align__(16) f16 Vl[2][256][40];  // [e][key], stride 40 (2-way banks)
  __shared__ __align__(16) f16 Psh[128][40];    // per-wave-private P rows

  // persistent Q fragments: rows 128*qt + 16*wave + l15 (scale pre-folded)
  const f16* qp = Q + ((size_t)(b * SS + qt * 128 + wave * 16 + l15)) * DD + lq * 8;
  f16x8 qf[16];
#pragma unroll
  for (int kk = 0; kk < 16; ++kk) qf[kk] = *(const f16x8*)(qp + kk * 32);

  const f16* Kb = K + (size_t)b * SS * DD;   // [key][d]
  const f16* Vb = Vt + (size_t)b * DD * SS;  // [e][s]
  const int ve = tid >> 2, vseg = tid & 3;   // V staging: e-row, 8-key segment

  for (int pass = 0; pass < 2; ++pass) {
    const f16* Vpb = Vb + (size_t)(pass * 256) * SS;
    // prologue: stage chunk 0 into buf 0
#pragma unroll
    for (int rr = 0; rr < 4; ++rr) {
      int row = wave * 4 + rr;
      gl_lds16(Kb + (size_t)row * DD + lane * 8, &Kl[0][row][lane * 8]);
    }
#pragma unroll
    for (int rd = 0; rd < 2; ++rd) {
      int e = rd * 128 + ve;
      *(f16x8*)&Vl[0][e][vseg * 8] = *(const f16x8*)(Vpb + (size_t)e * SS + vseg * 8);
    }
    __syncthreads();

    f32x4 acco[16] = {};
    float m_i[4] = {-1e30f, -1e30f, -1e30f, -1e30f};
    float l_i[4] = {0.f, 0.f, 0.f, 0.f};

    for (int it = 0; it < 64; ++it) {
      const int buf = it & 1;
      const int kb1 = (it + 1) * 32;  // next chunk's key base
      const bool pf = (it < 63);
      // prefetch next chunk: K DMA (no VGPRs), V into regs
      f16x8 vpre0, vpre1;
      if (pf) {
#pragma unroll
        for (int rr = 0; rr < 4; ++rr) {
          int row = wave * 4 + rr;
          gl_lds16(Kb + ((size_t)(kb1 + row)) * DD + lane * 8, &Kl[buf ^ 1][row][lane * 8]);
        }
        vpre0 = *(const f16x8*)(Vpb + (size_t)ve * SS + kb1 + vseg * 8);
        vpre1 = *(const f16x8*)(Vpb + (size_t)(128 + ve) * SS + kb1 + vseg * 8);
      }
      // ---- QK: S[16 rows][32 keys], rows 16*wave ----
      f32x4 sa0 = {}, sa1 = {};
#pragma unroll
      for (int kk = 0; kk < 16; ++kk) {
        f16x8 b0 = *(const f16x8*)&Kl[buf][l15][kk * 32 + lq * 8];
        f16x8 b1 = *(const f16x8*)&Kl[buf][16 + l15][kk * 32 + lq * 8];
        sa0 = __builtin_amdgcn_mfma_f32_16x16x32_f16(qf[kk], b0, sa0, 0, 0, 0);
        sa1 = __builtin_amdgcn_mfma_f32_16x16x32_f16(qf[kk], b1, sa1, 0, 0, 0);
      }
      // ---- in-register online softmax (rows lq*4+r, dup across l15) ----
      float mx[4], al[4], sum[4], p0[4], p1[4];
#pragma unroll
      for (int r = 0; r < 4; ++r) mx[r] = fmaxf(sa0[r], sa1[r]);
#pragma unroll
      for (int d = 1; d < 16; d <<= 1)
#pragma unroll
        for (int r = 0; r < 4; ++r) mx[r] = fmaxf(mx[r], __shfl_xor(mx[r], d));
#pragma unroll
      for (int r = 0; r < 4; ++r) {
        float mn = fmaxf(m_i[r], mx[r]);
        al[r] = __expf(m_i[r] - mn);
        m_i[r] = mn;
        p0[r] = __expf(sa0[r] - mn);
        p1[r] = __expf(sa1[r] - mn);
        sum[r] = p0[r] + p1[r];
      }
#pragma unroll
      for (int d = 1; d < 16; d <<= 1)
#pragma unroll
        for (int r = 0; r < 4; ++r) sum[r] += __shfl_xor(sum[r], d);
#pragma unroll
      for (int r = 0; r < 4; ++r) {
        l_i[r] = l_i[r] * al[r] + sum[r];
        Psh[16 * wave + 4 * lq + r][l15] = (f16)p0[r];
        Psh[16 * wave + 4 * lq + r][16 + l15] = (f16)p1[r];
      }
#pragma unroll
      for (int t = 0; t < 16; ++t)
#pragma unroll
        for (int r = 0; r < 4; ++r) acco[t][r] *= al[r];
      // ---- PV: O[16 rows][256 cols] += P[16x32] V[32 x 256] ----
      f16x8 pa = *(const f16x8*)&Psh[16 * wave + l15][lq * 8];
#pragma unroll
      for (int nn = 0; nn < 16; ++nn) {
        f16x8 vf = *(const f16x8*)&Vl[buf][nn * 16 + l15][lq * 8];
        acco[nn] = __builtin_amdgcn_mfma_f32_16x16x32_f16(pa, vf, acco[nn], 0, 0, 0);
      }
      // commit prefetched V, then the single per-iter barrier (drains K-DMA too)
      if (pf) {
        *(f16x8*)&Vl[buf ^ 1][ve][vseg * 8] = vpre0;
        *(f16x8*)&Vl[buf ^ 1][128 + ve][vseg * 8] = vpre1;
      }
      __syncthreads();
    }
    // ---- epilogue: O /= l, store fp32 ----
    float inv[4];
#pragma unroll
    for (int r = 0; r < 4; ++r) inv[r] = 1.0f / l_i[r];
    const size_t ob = ((size_t)(b * SS + qt * 128 + wave * 16 + 4 * lq)) * DD + pass * 256 + l15;
#pragma unroll
    for (int nn = 0; nn < 16; ++nn)
#pragma unroll
      for (int r = 0; r < 4; ++r)
        out[ob + (size_t)r * DD + nn * 16] = acco[nn][r] * inv[r];
    __syncthreads();  // before next pass re-stages buf 0
  }
}

extern "C" void kernel_launch(void* const* d_in, const int* in_sizes, int n_in,
                              void* d_out, int out_size, void* d_ws, size_t ws_size,
                              hipStream_t stream) {
  const float* x = (const float*)d_in[0];
  const float* Wq = (const float*)d_in[1];
  const float* bq = (const float*)d_in[2];
  const float* Wk = (const float*)d_in[3];
  const float* bk = (const float*)d_in[4];
  const float* Wv = (const float*)d_in[5];
  const float* bv = (const float*)d_in[6];
  float* out = (float*)d_out;
  f16* ws = (f16*)d_ws;
  const size_t NX = (size_t)NB * SS * DD;  // 16,777,216
  f16* xh = ws;
  f16* Qh = ws + NX;
  f16* Kh = ws + 2 * NX;
  f16* Vth = ws + 3 * NX;
  f16* WqT = ws + 4 * NX;
  f16* WkT = WqT + DD * DD;
  f16* WvT = WkT + DD * DD;

  cast_kernel<<<NX / 8 / 256, 256, 0, stream>>>(x, xh);
  dim3 tg(16, 16);
  transpose_kernel<<<tg, 256, 0, stream>>>(Wq, WqT);
  transpose_kernel<<<tg, 256, 0, stream>>>(Wk, WkT);
  transpose_kernel<<<tg, 256, 0, stream>>>(Wv, WvT);
  // Q = (x@Wq + bq) * 1/8  (scale folded, exact pow2)
  gemm_kernel<<<dim3(4, 256, 1), 256, 0, stream>>>(xh, 0, WqT, 0, Qh, 0, DD, bq, 0, 0.125f);
  // K = x@Wk + bk
  gemm_kernel<<<dim3(4, 256, 1), 256, 0, stream>>>(xh, 0, WkT, 0, Kh, 0, DD, bk, 0, 1.0f);
  // Vt[b][e][s] = WvT @ x[b]^T + bv[e]
  gemm_kernel<<<dim3(16, 4, NB), 256, 0, stream>>>(WvT, 0, xh, (long)SS * DD, Vth,
                                                   (long)DD * SS, SS, bv, 1, 1.0f);
  attn_kernel<<<256, 512, 0, stream>>>(Qh, Kh, Vth, out);
}